// Round 10
// baseline (120.911 us; speedup 1.0000x reference)
//
#include <hip/hip_runtime.h>

#define N_NODES 10000
#define N_EDGES 640000
#define D       128

#define GEMM_BLOCKS 157            // ceil(10000/64), 64-row M-tile
#define HB          32             // localhist chunks
#define CHUNK       20000          // edges per chunk (32*20000 = 640000)
#define PAD         256            // padded CSR bucket (max deg ~64+6sd << 256)
#define GROUPS      8              // XCD partitioning for scatter
#define NODES_PER_GROUP 1250
#define SBPG        128            // scatter blocks per group -> 1024 total

// pack two fp32 -> two bf16 (RNE) in one uint (low = a, high = b)
__device__ inline unsigned bf16pair(float a, float b) {
    unsigned ua = __float_as_uint(a), ub = __float_as_uint(b);
    ua = (ua + 0x7fffu + ((ua >> 16) & 1u)) >> 16;
    ub = (ub + 0x7fffu + ((ub >> 16) & 1u)) >> 16;
    return ua | (ub << 16);
}

union FusedSmem {
    float As[64][132];    // gemm A-tile (33.8 KB; stride 132 -> 2-way-max banks)
    int   cnt[N_NODES];   // hist counters (40 KB)
};

// ---------------------------------------------------------------------------
// Kernel 1 (fused): blocks [0,157) -> Y = nodes @ W stored bf16 (fp32 VALU;
// 4 rows x 8 cols per thread = 32 FMA per 32 B of W-loads, 2x the FMA
// density of the 2x8 version -> half the W re-read per FLOP);
// blocks [157,189) -> LDS local histogram + edge packing.
// pack[e] = sender(14b) | receiver(14b)<<14 | lrank(4b)<<28.
// ---------------------------------------------------------------------------
__global__ __launch_bounds__(256) void gemm_hist_kernel(const float* __restrict__ nodes,
                                                        const float* __restrict__ Wm,
                                                        unsigned* __restrict__ Yb,
                                                        const int* __restrict__ senders,
                                                        const int* __restrict__ receivers,
                                                        unsigned* __restrict__ pack,
                                                        int* __restrict__ bcnt) {
    __shared__ FusedSmem sm;
    const int t = threadIdx.x;

    if (blockIdx.x < GEMM_BLOCKS) {
        const int row0 = blockIdx.x * 64;

        // stage A tile: 64x128 floats = 2048 float4, 8 per thread
        for (int i = t; i < 2048; i += 256) {
            int r  = i >> 5;
            int c  = i & 31;
            int gr = row0 + r;
            float4 v = make_float4(0.f, 0.f, 0.f, 0.f);
            if (gr < N_NODES) v = ((const float4*)nodes)[gr * 32 + c];
            *((float4*)&sm.As[r][c * 4]) = v;
        }
        __syncthreads();

        const int tx = t & 15;        // col group: cols tx*8 .. tx*8+7
        const int ty = t >> 4;        // row group: rows ty*4 .. ty*4+3
        const int r0 = ty * 4;

        float acc[4][8];
#pragma unroll
        for (int i = 0; i < 4; i++)
#pragma unroll
            for (int j = 0; j < 8; j++) acc[i][j] = 0.f;

        const float4* W4 = (const float4*)Wm;
#pragma unroll 4
        for (int k = 0; k < 128; k++) {
            float  a0 = sm.As[r0][k];
            float  a1 = sm.As[r0 + 1][k];
            float  a2 = sm.As[r0 + 2][k];
            float  a3 = sm.As[r0 + 3][k];
            float4 w0 = W4[k * 32 + tx * 2];
            float4 w1 = W4[k * 32 + tx * 2 + 1];
            float  wv[8] = {w0.x, w0.y, w0.z, w0.w, w1.x, w1.y, w1.z, w1.w};
#pragma unroll
            for (int j = 0; j < 8; j++) {
                acc[0][j] += a0 * wv[j];
                acc[1][j] += a1 * wv[j];
                acc[2][j] += a2 * wv[j];
                acc[3][j] += a3 * wv[j];
            }
        }

#pragma unroll
        for (int i = 0; i < 4; i++) {
            int gr = row0 + r0 + i;
            if (gr < N_NODES) {
                uint4 o;
                o.x = bf16pair(acc[i][0], acc[i][1]);
                o.y = bf16pair(acc[i][2], acc[i][3]);
                o.z = bf16pair(acc[i][4], acc[i][5]);
                o.w = bf16pair(acc[i][6], acc[i][7]);
                ((uint4*)Yb)[gr * 16 + tx] = o;   // row = 128 bf16 = 16 uint4
            }
        }
    } else {
        const int b = blockIdx.x - GEMM_BLOCKS;
        for (int n = t; n < N_NODES; n += 256) sm.cnt[n] = 0;
        __syncthreads();
        const int base = b * CHUNK;
        for (int i = t; i < CHUNK; i += 256) {
            int r = receivers[base + i];
            int s = senders[base + i];
            int l = atomicAdd(&sm.cnt[r], 1);          // LDS atomic: ns-latency
            pack[base + i] = (unsigned)s | ((unsigned)r << 14) | ((unsigned)l << 28);
        }
        __syncthreads();
        int* dst = bcnt + b * N_NODES;
        for (int n = t; n < N_NODES; n += 256) dst[n] = sm.cnt[n];
    }
}

// ---------------------------------------------------------------------------
// Kernel 2: column scan, 2 threads per node: each scans 16 of the 32 chunks
// (independent loads, half chain depth), partials combined via 2-lane __shfl
// (2-aligned pairs never straddle a wave; guard group-uniform). Each (b,n)
// cell owned by exactly one thread -> in-place safe.
// ---------------------------------------------------------------------------
__global__ __launch_bounds__(256) void colscan_kernel(int* __restrict__ bcnt,
                                                      int* __restrict__ deg) {
    const int g = blockIdx.x * 256 + threadIdx.x;
    const int n = g >> 1;
    const int q = g & 1;
    if (n >= N_NODES) return;

    int pre[16];
    int s = 0;
#pragma unroll
    for (int j = 0; j < 16; j++) {
        int v = bcnt[(q * 16 + j) * N_NODES + n];
        pre[j] = s;
        s += v;
    }

    const int lane = threadIdx.x & 63;
    int s0  = __shfl(s, lane & ~1);      // partner's (q=0) total
    int off = q ? s0 : 0;

#pragma unroll
    for (int j = 0; j < 16; j++)
        bcnt[(q * 16 + j) * N_NODES + n] = off + pre[j];
    if (q == 1) deg[n] = off + s;
}

// ---------------------------------------------------------------------------
// Kernel 3: XCD-partitioned scatter into padded CSR — atomic-free.
// Reads only pack (2.56 MB x 8 groups, L3-served). Group x = blockIdx&7
// stores only receivers in [x*1250,(x+1)*1250) -> disjoint csr regions per
// XCD. pos = (r<<8) + bcnt[chunk][r] + lrank.
// ---------------------------------------------------------------------------
__global__ __launch_bounds__(256) void scatter_kernel(const unsigned* __restrict__ pack,
                                                      const int* __restrict__ bcnt,
                                                      int* __restrict__ csr) {
    const int x  = blockIdx.x & 7;
    const int bg = blockIdx.x >> 3;
    const int lo = x * NODES_PER_GROUP;
    const int hi = lo + NODES_PER_GROUP;

    for (int i = bg * 256 + threadIdx.x; i < N_EDGES / 4; i += SBPG * 256) {
        int b = i / (CHUNK / 4);              // CHUNK%4==0: uint4 never straddles
        const int* pre = bcnt + b * N_NODES;
        uint4 p = ((const uint4*)pack)[i];
#pragma unroll
        for (int q = 0; q < 4; q++) {
            unsigned wd = (q == 0) ? p.x : (q == 1) ? p.y : (q == 2) ? p.z : p.w;
            int r = (int)((wd >> 14) & 0x3fffu);
            if (r >= lo && r < hi) {
                int s = (int)(wd & 0x3fffu);
                int l = (int)(wd >> 28);
                csr[(r << 8) + pre[r] + l] = s;
            }
        }
    }
}

// ---------------------------------------------------------------------------
// Kernel 4: pull-gather over bf16 Y — 2 nodes per 128-thread block.
// d4 = t&15 (16 B = 8 bf16 per lane), ep = t>>4 (8 edges in flight).
// ---------------------------------------------------------------------------
__global__ __launch_bounds__(128) void gather_kernel(const unsigned* __restrict__ Yb,
                                                     const int* __restrict__ deg,
                                                     const int* __restrict__ csr,
                                                     const float* __restrict__ bias,
                                                     float* __restrict__ out) {
    const int t  = threadIdx.x;
    const int d4 = t & 15;
    const int ep = t >> 4;

    __shared__ int   lds_s[PAD];
    __shared__ float red[8][128];

#pragma unroll
    for (int nn = 0; nn < 2; nn++) {
        const int n   = blockIdx.x * 2 + nn;           // grid=5000, covers 10000
        const int dg  = deg[n];
        const int lim = min(dg, PAD);

        for (int i = t; i < lim; i += 128) lds_s[i] = csr[(n << 8) + i];
        __syncthreads();

        float acc[8];
#pragma unroll
        for (int k = 0; k < 8; k++) acc[k] = 0.f;

        for (int j = ep; j < lim; j += 8) {
            int   s = lds_s[j];
            uint4 v = ((const uint4*)Yb)[s * 16 + d4];   // 8 bf16 = 16 B
            acc[0] += __uint_as_float(v.x << 16);
            acc[1] += __uint_as_float(v.x & 0xffff0000u);
            acc[2] += __uint_as_float(v.y << 16);
            acc[3] += __uint_as_float(v.y & 0xffff0000u);
            acc[4] += __uint_as_float(v.z << 16);
            acc[5] += __uint_as_float(v.z & 0xffff0000u);
            acc[6] += __uint_as_float(v.w << 16);
            acc[7] += __uint_as_float(v.w & 0xffff0000u);
        }

        ((float4*)&red[ep][d4 * 8])[0] = make_float4(acc[0], acc[1], acc[2], acc[3]);
        ((float4*)&red[ep][d4 * 8])[1] = make_float4(acc[4], acc[5], acc[6], acc[7]);
        __syncthreads();

        float sum = 0.f;
#pragma unroll
        for (int e = 0; e < 8; e++) sum += red[e][t];
        float inv = 1.0f / (float)max(dg, 1);
        out[n * 128 + t] = sum * inv + bias[t];
        __syncthreads();   // protect lds_s/red before next node's restage
    }
}

// ---------------------------------------------------------------------------
extern "C" void kernel_launch(void* const* d_in, const int* in_sizes, int n_in,
                              void* d_out, int out_size, void* d_ws, size_t ws_size,
                              hipStream_t stream) {
    const float* nodes     = (const float*)d_in[0];
    const int*   senders   = (const int*)  d_in[1];
    const int*   receivers = (const int*)  d_in[2];
    const float* Wm        = (const float*)d_in[3];
    const float* bias      = (const float*)d_in[4];
    float*       out       = (float*)d_out;

    // workspace layout (bytes)
    char*     w    = (char*)d_ws;
    unsigned* Yb   = (unsigned*)(w);               // bf16 Y:       2,560,000
    unsigned* pack = (unsigned*)(w + 2560000);     //               2,560,000
    int*      bcnt = (int*)(w + 5120000);          // 32x10000x4:   1,280,000
    int*      deg  = (int*)(w + 6400000);          //                  40,000
    int*      csr  = (int*)(w + 6440448);          // 10000x256x4: 10,240,000

    gemm_hist_kernel<<<GEMM_BLOCKS + HB, 256, 0, stream>>>(nodes, Wm, Yb,
                                                           senders, receivers,
                                                           pack, bcnt);
    colscan_kernel  <<<(2 * N_NODES + 255) / 256, 256, 0, stream>>>(bcnt, deg);
    scatter_kernel  <<<GROUPS * SBPG, 256, 0, stream>>>(pack, bcnt, csr);
    gather_kernel   <<<N_NODES / 2, 128, 0, stream>>>(Yb, deg, csr, bias, out);
}

// Round 11
// 109.676 us; speedup vs baseline: 1.1024x; 1.1024x over previous
//
#include <hip/hip_runtime.h>

#define N_NODES 10000
#define N_EDGES 640000
#define D       128

#define GEMM_BLOCKS 313            // ceil(10000/32), 32-row M-tile (conflict-free banks)
#define HB          64             // localhist chunks
#define CHUNK       10000          // edges per chunk (64*10000 = 640000)
#define PAD         256            // padded CSR bucket (max deg ~64+6sd << 256)
#define GROUPS      8              // XCD partitioning for scatter
#define NODES_PER_GROUP 1250
#define SBPG        128            // scatter blocks per group -> 1024 total

// pack two fp32 -> two bf16 (RNE) in one uint (low = a, high = b)
__device__ inline unsigned bf16pair(float a, float b) {
    unsigned ua = __float_as_uint(a), ub = __float_as_uint(b);
    ua = (ua + 0x7fffu + ((ua >> 16) & 1u)) >> 16;
    ub = (ub + 0x7fffu + ((ub >> 16) & 1u)) >> 16;
    return ua | (ub << 16);
}

union FusedSmem {
    float As[32][132];    // gemm A-tile (16.9 KB); r0=2*ty -> banks k,k+8,k+16,k+24: conflict-free
    int   cnt[N_NODES];   // hist counters (40 KB)
};

// ---------------------------------------------------------------------------
// Kernel 1 (fused): blocks [0,313) -> Y = nodes @ W stored bf16 (fp32 VALU,
// 2 rows x 8 cols per thread — R10's 4-row variant caused 8-way LDS bank
// conflicts, reverted); blocks [313,377) -> LDS local histogram + packing.
// pack[e] = sender(14b) | receiver(14b)<<14 | lrank(4b)<<28.
// ---------------------------------------------------------------------------
__global__ __launch_bounds__(256) void gemm_hist_kernel(const float* __restrict__ nodes,
                                                        const float* __restrict__ Wm,
                                                        unsigned* __restrict__ Yb,
                                                        const int* __restrict__ senders,
                                                        const int* __restrict__ receivers,
                                                        unsigned* __restrict__ pack,
                                                        int* __restrict__ bcnt) {
    __shared__ FusedSmem sm;
    const int t = threadIdx.x;

    if (blockIdx.x < GEMM_BLOCKS) {
        const int row0 = blockIdx.x * 32;

        for (int i = t; i < 1024; i += 256) {
            int r  = i >> 5;
            int c  = i & 31;
            int gr = row0 + r;
            float4 v = make_float4(0.f, 0.f, 0.f, 0.f);
            if (gr < N_NODES) v = ((const float4*)nodes)[gr * 32 + c];
            *((float4*)&sm.As[r][c * 4]) = v;
        }
        __syncthreads();

        const int tx = t & 15;
        const int ty = t >> 4;
        const int c0 = tx * 8;
        const int r0 = ty * 2;

        float acc[2][8];
#pragma unroll
        for (int i = 0; i < 2; i++)
#pragma unroll
            for (int j = 0; j < 8; j++) acc[i][j] = 0.f;

        const float4* W4 = (const float4*)Wm;
#pragma unroll 4
        for (int k = 0; k < 128; k++) {
            float  a0 = sm.As[r0][k];
            float  a1 = sm.As[r0 + 1][k];
            float4 w0 = W4[k * 32 + tx * 2];
            float4 w1 = W4[k * 32 + tx * 2 + 1];
            float  wv[8] = {w0.x, w0.y, w0.z, w0.w, w1.x, w1.y, w1.z, w1.w};
#pragma unroll
            for (int j = 0; j < 8; j++) {
                acc[0][j] += a0 * wv[j];
                acc[1][j] += a1 * wv[j];
            }
        }

#pragma unroll
        for (int i = 0; i < 2; i++) {
            int gr = row0 + r0 + i;
            if (gr < N_NODES) {
                uint4 o;
                o.x = bf16pair(acc[i][0], acc[i][1]);
                o.y = bf16pair(acc[i][2], acc[i][3]);
                o.z = bf16pair(acc[i][4], acc[i][5]);
                o.w = bf16pair(acc[i][6], acc[i][7]);
                ((uint4*)Yb)[gr * 16 + (c0 >> 3)] = o;
            }
        }
    } else {
        const int b = blockIdx.x - GEMM_BLOCKS;
        for (int n = t; n < N_NODES; n += 256) sm.cnt[n] = 0;
        __syncthreads();
        const int base = b * CHUNK;
        for (int i = t; i < CHUNK; i += 256) {
            int r = receivers[base + i];
            int s = senders[base + i];
            int l = atomicAdd(&sm.cnt[r], 1);          // LDS atomic: ns-latency
            pack[base + i] = (unsigned)s | ((unsigned)r << 14) | ((unsigned)l << 28);
        }
        __syncthreads();
        int* dst = bcnt + b * N_NODES;
        for (int n = t; n < N_NODES; n += 256) dst[n] = sm.cnt[n];
    }
}

// ---------------------------------------------------------------------------
// Kernel 2: column scan, 4 threads per node: each scans 16 of the 64 chunks
// (independent loads, 1/4 chain depth), partials combined via intra-wave
// __shfl (4-aligned groups never straddle a wave; guard group-uniform).
// Each (b,n) cell owned by exactly one thread -> in-place safe.
// ---------------------------------------------------------------------------
__global__ __launch_bounds__(256) void colscan_kernel(int* __restrict__ bcnt,
                                                      int* __restrict__ deg) {
    const int g = blockIdx.x * 256 + threadIdx.x;
    const int n = g >> 2;
    const int q = g & 3;
    if (n >= N_NODES) return;

    int pre[16];
    int s = 0;
#pragma unroll
    for (int j = 0; j < 16; j++) {
        int v = bcnt[(q * 16 + j) * N_NODES + n];
        pre[j] = s;
        s += v;
    }

    const int lane = threadIdx.x & 63;
    const int gb   = lane & ~3;          // group base lane
    int s0 = __shfl(s, gb + 0);
    int s1 = __shfl(s, gb + 1);
    int s2 = __shfl(s, gb + 2);
    int off = (q > 0 ? s0 : 0) + (q > 1 ? s1 : 0) + (q > 2 ? s2 : 0);

#pragma unroll
    for (int j = 0; j < 16; j++)
        bcnt[(q * 16 + j) * N_NODES + n] = off + pre[j];
    if (q == 3) deg[n] = off + s;
}

// ---------------------------------------------------------------------------
// Kernel 3: XCD-partitioned scatter into padded CSR — atomic-free.
// Reads only pack (2.56 MB x 8 groups, L3-served). Group x = blockIdx&7
// stores only receivers in [x*1250,(x+1)*1250) -> disjoint csr regions per
// XCD. pos = (r<<8) + bcnt[chunk][r] + lrank.
// ---------------------------------------------------------------------------
__global__ __launch_bounds__(256) void scatter_kernel(const unsigned* __restrict__ pack,
                                                      const int* __restrict__ bcnt,
                                                      int* __restrict__ csr) {
    const int x  = blockIdx.x & 7;
    const int bg = blockIdx.x >> 3;
    const int lo = x * NODES_PER_GROUP;
    const int hi = lo + NODES_PER_GROUP;

    for (int i = bg * 256 + threadIdx.x; i < N_EDGES / 4; i += SBPG * 256) {
        int b = i / (CHUNK / 4);              // CHUNK%4==0: uint4 never straddles
        const int* pre = bcnt + b * N_NODES;
        uint4 p = ((const uint4*)pack)[i];
#pragma unroll
        for (int q = 0; q < 4; q++) {
            unsigned wd = (q == 0) ? p.x : (q == 1) ? p.y : (q == 2) ? p.z : p.w;
            int r = (int)((wd >> 14) & 0x3fffu);
            if (r >= lo && r < hi) {
                int s = (int)(wd & 0x3fffu);
                int l = (int)(wd >> 28);
                csr[(r << 8) + pre[r] + l] = s;
            }
        }
    }
}

// ---------------------------------------------------------------------------
// Kernel 4: pull-gather over bf16 Y — 2 nodes per 128-thread block.
// d4 = t&15 (16 B = 8 bf16 per lane), ep = t>>4 (8 edges in flight).
// ---------------------------------------------------------------------------
__global__ __launch_bounds__(128) void gather_kernel(const unsigned* __restrict__ Yb,
                                                     const int* __restrict__ deg,
                                                     const int* __restrict__ csr,
                                                     const float* __restrict__ bias,
                                                     float* __restrict__ out) {
    const int t  = threadIdx.x;
    const int d4 = t & 15;
    const int ep = t >> 4;

    __shared__ int   lds_s[PAD];
    __shared__ float red[8][128];

#pragma unroll
    for (int nn = 0; nn < 2; nn++) {
        const int n   = blockIdx.x * 2 + nn;           // grid=5000, covers 10000
        const int dg  = deg[n];
        const int lim = min(dg, PAD);

        for (int i = t; i < lim; i += 128) lds_s[i] = csr[(n << 8) + i];
        __syncthreads();

        float acc[8];
#pragma unroll
        for (int k = 0; k < 8; k++) acc[k] = 0.f;

        for (int j = ep; j < lim; j += 8) {
            int   s = lds_s[j];
            uint4 v = ((const uint4*)Yb)[s * 16 + d4];   // 8 bf16 = 16 B
            acc[0] += __uint_as_float(v.x << 16);
            acc[1] += __uint_as_float(v.x & 0xffff0000u);
            acc[2] += __uint_as_float(v.y << 16);
            acc[3] += __uint_as_float(v.y & 0xffff0000u);
            acc[4] += __uint_as_float(v.z << 16);
            acc[5] += __uint_as_float(v.z & 0xffff0000u);
            acc[6] += __uint_as_float(v.w << 16);
            acc[7] += __uint_as_float(v.w & 0xffff0000u);
        }

        ((float4*)&red[ep][d4 * 8])[0] = make_float4(acc[0], acc[1], acc[2], acc[3]);
        ((float4*)&red[ep][d4 * 8])[1] = make_float4(acc[4], acc[5], acc[6], acc[7]);
        __syncthreads();

        float sum = 0.f;
#pragma unroll
        for (int e = 0; e < 8; e++) sum += red[e][t];
        float inv = 1.0f / (float)max(dg, 1);
        out[n * 128 + t] = sum * inv + bias[t];
        __syncthreads();   // protect lds_s/red before next node's restage
    }
}

// ---------------------------------------------------------------------------
extern "C" void kernel_launch(void* const* d_in, const int* in_sizes, int n_in,
                              void* d_out, int out_size, void* d_ws, size_t ws_size,
                              hipStream_t stream) {
    const float* nodes     = (const float*)d_in[0];
    const int*   senders   = (const int*)  d_in[1];
    const int*   receivers = (const int*)  d_in[2];
    const float* Wm        = (const float*)d_in[3];
    const float* bias      = (const float*)d_in[4];
    float*       out       = (float*)d_out;

    // workspace layout (bytes)
    char*     w    = (char*)d_ws;
    unsigned* Yb   = (unsigned*)(w);               // bf16 Y:       2,560,000
    unsigned* pack = (unsigned*)(w + 2560000);     //               2,560,000
    int*      bcnt = (int*)(w + 5120000);          // 64x10000x4:   2,560,000
    int*      deg  = (int*)(w + 7680000);          //                  40,000
    int*      csr  = (int*)(w + 7720448);          // 10000x256x4: 10,240,000

    gemm_hist_kernel<<<GEMM_BLOCKS + HB, 256, 0, stream>>>(nodes, Wm, Yb,
                                                           senders, receivers,
                                                           pack, bcnt);
    colscan_kernel  <<<(4 * N_NODES + 255) / 256, 256, 0, stream>>>(bcnt, deg);
    scatter_kernel  <<<GROUPS * SBPG, 256, 0, stream>>>(pack, bcnt, csr);
    gather_kernel   <<<N_NODES / 2, 128, 0, stream>>>(Yb, deg, csr, bias, out);
}